// Round 9
// baseline (397.839 us; speedup 1.0000x reference)
//
#include <hip/hip_runtime.h>
#include <hip/hip_bf16.h>
#include <cstdint>
#include <cstddef>

#define DIM    1024
#define NHEAD  16
#define HDIM   64
#define HIDDEN 4096
#define TSEQ   2048
#define TOKENS 4096  // B*T

typedef __attribute__((ext_vector_type(4))) float  f32x4;
typedef __attribute__((ext_vector_type(8))) short  short8;
typedef __attribute__((ext_vector_type(8))) __bf16 bf16x8;

__device__ __forceinline__ short f2bf(float f) {
    union { float f; uint32_t u; } v; v.f = f;
    uint32_t u = v.u;
    uint32_t r = (u + 0x7fffu + ((u >> 16) & 1u)) >> 16;  // RNE
    return (short)r;
}

__device__ __forceinline__ f32x4 mfma_bf16(short8 a, short8 b, f32x4 c) {
    return __builtin_amdgcn_mfma_f32_16x16x32_bf16(
        __builtin_bit_cast(bf16x8, a), __builtin_bit_cast(bf16x8, b), c, 0, 0, 0);
}

__device__ __forceinline__ void ldg_lds16(const void* g, void* l) {
    __builtin_amdgcn_global_load_lds(
        (const __attribute__((address_space(1))) void*)g,
        (__attribute__((address_space(3))) void*)l, 16, 0, 0);
}

// lgkm-only barrier (does NOT drain vmem - keeps glds DMAs in flight)
__device__ __forceinline__ void barrier_lds() {
    asm volatile("s_waitcnt lgkmcnt(0)\n\ts_barrier" ::: "memory");
}

// ---------------------------------------------------------------------------
// Weight transpose + fp32->bf16 convert:  W[K][N] -> Wt[N][K] (bf16)
// ---------------------------------------------------------------------------
__global__ __launch_bounds__(256) void transpose_w(
    const float* __restrict__ W, short* __restrict__ Wt, int K, int N)
{
    __shared__ float tile[64][65];
    const int tid = threadIdx.x;
    const int n0 = blockIdx.x * 64, k0 = blockIdx.y * 64;
    for (int i = tid; i < 4096; i += 256) {
        int r = i >> 6, c = i & 63;
        tile[r][c] = W[(size_t)(k0 + r) * N + n0 + c];
    }
    __syncthreads();
    for (int i = tid; i < 4096; i += 256) {
        int r = i >> 6, c = i & 63;
        Wt[(size_t)(n0 + r) * K + k0 + c] = f2bf(tile[c][r]);
    }
}

// ---------------------------------------------------------------------------
// V transpose: qkv [4096][3072] (V at col 2048 + h*64) -> Vt[bh][64][2048]
// ---------------------------------------------------------------------------
__global__ __launch_bounds__(256) void transpose_v(
    const short* __restrict__ qkv, short* __restrict__ Vt)
{
    __shared__ short tile[64][72];
    const int tid = threadIdx.x;
    const int s0 = blockIdx.x * 64, bh = blockIdx.y;
    const int b = bh >> 4, h = bh & 15;
    const short* src = qkv + ((size_t)(b * TSEQ + s0)) * 3072 + 2048 + h * 64;
    for (int i = tid; i < 512; i += 256) {
        int r = i >> 3, cg = i & 7;
        *(short8*)&tile[r][cg * 8] = *(const short8*)(src + (size_t)r * 3072 + cg * 8);
    }
    __syncthreads();
    short* dst = Vt + ((size_t)bh * 64) * TSEQ + s0;
    for (int i = tid; i < 512; i += 256) {
        int d = i >> 3, sg = i & 7;
        short8 o;
#pragma unroll
        for (int j = 0; j < 8; ++j) o[j] = tile[sg * 8 + j][d];
        *(short8*)(dst + (size_t)d * TSEQ + sg * 8) = o;
    }
}

// ---------------------------------------------------------------------------
// RMSNorm: fp32 in -> bf16 out. One block per token.
// ---------------------------------------------------------------------------
__global__ __launch_bounds__(256) void rmsnorm_k(
    const float* __restrict__ x, const float* __restrict__ g, short* __restrict__ out)
{
    const int t = blockIdx.x, tid = threadIdx.x;
    const int wave = tid >> 6, lane = tid & 63;
    const float4 v = ((const float4*)(x + (size_t)t * DIM))[tid];
    float ss = v.x * v.x + v.y * v.y + v.z * v.z + v.w * v.w;
#pragma unroll
    for (int d = 1; d < 64; d <<= 1) ss += __shfl_xor(ss, d, 64);
    __shared__ float red[4];
    if (lane == 0) red[wave] = ss;
    __syncthreads();
    float tot = red[0] + red[1] + red[2] + red[3];
    float rn = rsqrtf(tot * (1.0f / (float)DIM) + 1e-6f);
    const float4 gv = ((const float4*)g)[tid];
    short4 ov = make_short4(f2bf(v.x * rn * gv.x), f2bf(v.y * rn * gv.y),
                            f2bf(v.z * rn * gv.z), f2bf(v.w * rn * gv.w));
    ((short4*)(out + (size_t)t * DIM))[tid] = ov;
}

// ---------------------------------------------------------------------------
// bf16 GEMM: C[M][N] = A[M][K] * Bt[N][K]^T, 128x128 tile, BK=32, 4 waves.
// AITER-style K-loop: global_load_lds DMA into double-buffered LDS (no
// ds_writes, no prefetch VGPRs), manual fine-grained s_waitcnt vmcnt(4)
// (waits ONLY the current tile's 4 DMAs; next tile's stay in flight),
// lgkm-only barriers. Iter k:
//   vmcnt(4); s_barrier; ds_read(buf k)+MFMA; lgkm-barrier; glds(tile k+2).
// Grid is m-fastest (m0=blockIdx.x): with lin%8 XCD round-robin each XCD
// pins a fixed m-subset -> its A rows stay L2-resident across all n
// (r8 n-fastest layout re-fetched the whole A per XCD: FETCH 135 MB).
// EPI: 0 = bf16 out, 1 = fp32 out + fp32 residual, 2 = SiLU -> bf16 out,
//      3 = fp32 partial out at Cout + z*M*N (split-K)
// ---------------------------------------------------------------------------
template <int EPI>
__global__ __launch_bounds__(256) void gemm_bt(
    const short* __restrict__ A, const short* __restrict__ Bt,
    void* __restrict__ Cout, const float* __restrict__ res,
    int M, int N, int K)
{
    __shared__ short As[2][128 * 32];
    __shared__ short Bs[2][128 * 32];
    const int tid  = threadIdx.x;
    const int wave = tid >> 6, lane = tid & 63;
    const int lm = lane & 15, quad = lane >> 4;
    const int wm = wave & 1, wn = wave >> 1;
    const int m0 = blockIdx.x * 128, n0 = blockIdx.y * 128;  // m fastest!
    const int Ksl = K / gridDim.z;
    const int kbeg = blockIdx.z * Ksl;
    const int nIter = Ksl >> 5;

    const f32x4 zero = {0.f, 0.f, 0.f, 0.f};
    f32x4 acc[4][4];
#pragma unroll
    for (int i = 0; i < 4; ++i)
#pragma unroll
        for (int j = 0; j < 4; ++j) acc[i][j] = zero;

    // staging: thread covers rows lrow, lrow+16 / cols lcol..lcol+7 of the
    // 128x32 tiles; glds LDS dest is wave-uniform base + lane*16B, which
    // matches row-major [row][col] for this lane->(row,col) map.
    const int lrow = wave * 32 + (lane >> 2);
    const int lcol = (lane & 3) * 8;
    const short* Apre = A + (size_t)(m0 + lrow) * K + kbeg + lcol;
    const short* Bpre = Bt + (size_t)(n0 + lrow) * K + kbeg + lcol;

    auto stage = [&](int buf) {
        ldg_lds16(Apre, &As[buf][(wave * 32) * 32]);
        ldg_lds16(Apre + (size_t)16 * K, &As[buf][(wave * 32 + 16) * 32]);
        ldg_lds16(Bpre, &Bs[buf][(wave * 32) * 32]);
        ldg_lds16(Bpre + (size_t)16 * K, &Bs[buf][(wave * 32 + 16) * 32]);
        Apre += 32; Bpre += 32;
    };

    stage(0);  // tile 0
    stage(1);  // tile 1

    for (int it = 0; it < nIter; ++it) {
        const int cur = it & 1;
        // wait only the current tile's 4 DMAs (next tile's 4 stay in flight)
        asm volatile("s_waitcnt vmcnt(4)" ::: "memory");
        asm volatile("s_barrier" ::: "memory");
        const short* as = As[cur];
        const short* bs = Bs[cur];
        short8 af[4], bf[4];
#pragma unroll
        for (int mt = 0; mt < 4; ++mt)
            af[mt] = *(const short8*)&as[(wm * 64 + mt * 16 + lm) * 32 + quad * 8];
#pragma unroll
        for (int nt = 0; nt < 4; ++nt)
            bf[nt] = *(const short8*)&bs[(wn * 64 + nt * 16 + lm) * 32 + quad * 8];
#pragma unroll
        for (int mt = 0; mt < 4; ++mt)
#pragma unroll
            for (int nt = 0; nt < 4; ++nt)
                acc[mt][nt] = mfma_bf16(af[mt], bf[nt], acc[mt][nt]);
        barrier_lds();                      // all waves' ds_reads of buf done
        if (it + 2 < nIter) stage(cur);     // refill the buffer just drained
    }

#pragma unroll
    for (int mt = 0; mt < 4; ++mt) {
#pragma unroll
        for (int r = 0; r < 4; ++r) {
            const int row = m0 + wm * 64 + mt * 16 + quad * 4 + r;
#pragma unroll
            for (int nt = 0; nt < 4; ++nt) {
                const int col = n0 + wn * 64 + nt * 16 + lm;
                const size_t idx = (size_t)row * N + col;
                const float v = acc[mt][nt][r];
                if constexpr (EPI == 0) {
                    ((short*)Cout)[idx] = f2bf(v);
                } else if constexpr (EPI == 1) {
                    ((float*)Cout)[idx] = res[idx] + v;
                } else if constexpr (EPI == 2) {
                    ((short*)Cout)[idx] = f2bf(v / (1.0f + __expf(-v)));
                } else {
                    ((float*)Cout)[(size_t)blockIdx.z * M * N + idx] = v;
                }
            }
        }
    }
}

// ---------------------------------------------------------------------------
// Split-K combine: out = res + p[0] + p[1]
// ---------------------------------------------------------------------------
__global__ __launch_bounds__(256) void combine_k(
    const float* __restrict__ p, const float* __restrict__ res,
    float* __restrict__ out, int n)
{
    const int i = blockIdx.x * 256 + threadIdx.x;
    if (i * 4 < n) {
        float4 a = ((const float4*)res)[i];
        float4 b = ((const float4*)p)[i];
        float4 c = ((const float4*)(p + n))[i];
        float4 o = make_float4(a.x + b.x + c.x, a.y + b.y + c.y,
                               a.z + b.z + c.z, a.w + b.w + c.w);
        ((float4*)out)[i] = o;
    }
}

// ---------------------------------------------------------------------------
// Fused split-K combine + RMSNorm: one block per token.
// ---------------------------------------------------------------------------
__global__ __launch_bounds__(256) void combine_rms(
    const float* __restrict__ p, const float* __restrict__ res,
    const float* __restrict__ g, float* __restrict__ x2out,
    short* __restrict__ nout)
{
    const int t = blockIdx.x, tid = threadIdx.x;
    const int wave = tid >> 6, lane = tid & 63;
    const size_t base = (size_t)t * DIM / 4;
    float4 a = ((const float4*)res)[base + tid];
    float4 b = ((const float4*)p)[base + tid];
    float4 c = ((const float4*)p)[(size_t)TOKENS * DIM / 4 + base + tid];
    float4 v = make_float4(a.x + b.x + c.x, a.y + b.y + c.y,
                           a.z + b.z + c.z, a.w + b.w + c.w);
    ((float4*)x2out)[base + tid] = v;
    float ss = v.x * v.x + v.y * v.y + v.z * v.z + v.w * v.w;
#pragma unroll
    for (int d = 1; d < 64; d <<= 1) ss += __shfl_xor(ss, d, 64);
    __shared__ float red[4];
    if (lane == 0) red[wave] = ss;
    __syncthreads();
    float tot = red[0] + red[1] + red[2] + red[3];
    float rn = rsqrtf(tot * (1.0f / (float)DIM) + 1e-6f);
    const float4 gv = ((const float4*)g)[tid];
    short4 ov = make_short4(f2bf(v.x * rn * gv.x), f2bf(v.y * rn * gv.y),
                            f2bf(v.z * rn * gv.z), f2bf(v.w * rn * gv.w));
    ((short4*)nout)[base + tid] = ov;
}

// ---------------------------------------------------------------------------
// Flash attention, causal, fixed-max softmax. 128-thread block = 2 waves x
// 32 q-rows; one block per (bh, 64-row q-tile). Register K/V prefetch.
// ---------------------------------------------------------------------------
#define LP 72
__global__ __launch_bounds__(128) void attn_k(
    const short* __restrict__ qkv, const short* __restrict__ Vt,
    short* __restrict__ out)
{
    __shared__ short Qs[64 * LP];
    __shared__ short Ks[64 * LP];
    __shared__ short Vts[64 * LP];
    __shared__ short Ps[2][32 * LP];

    const int tid = threadIdx.x, wave = tid >> 6, lane = tid & 63;
    const int lm = lane & 15, quad = lane >> 4;
    const int bh = blockIdx.x;
    const int qt = (gridDim.y - 1) - blockIdx.y;  // heavy blocks first
    const int b = bh >> 4, h = bh & 15;
    const int q0 = qt * 64;

    const int rr = tid >> 3, cg = tid & 7;

    const short* qbase = qkv + ((size_t)(b * TSEQ + q0)) * 3072 + h * 64;
#pragma unroll
    for (int j = 0; j < 4; ++j)
        *(short8*)&Qs[(rr + j * 16) * LP + cg * 8] =
            *(const short8*)(qbase + (size_t)(rr + j * 16) * 3072 + cg * 8);

    const short* kb  = qkv + (size_t)b * TSEQ * 3072 + 1024 + h * 64;
    const short* vtb = Vt + (size_t)bh * 64 * TSEQ;

    short8 kr[4], vr[4];
#pragma unroll
    for (int j = 0; j < 4; ++j) {
        kr[j] = *(const short8*)(kb + (size_t)(rr + j * 16) * 3072 + cg * 8);
        vr[j] = *(const short8*)(vtb + (size_t)(rr + j * 16) * TSEQ + cg * 8);
    }

    const f32x4 zero = {0.f, 0.f, 0.f, 0.f};
    f32x4 o_acc[2][4];
#pragma unroll
    for (int mt = 0; mt < 2; ++mt)
#pragma unroll
        for (int t = 0; t < 4; ++t) o_acc[mt][t] = zero;
    float lsum[2][4] = {{0.f, 0.f, 0.f, 0.f}, {0.f, 0.f, 0.f, 0.f}};

    for (int st = 0; st <= qt; ++st) {
        __syncthreads();
#pragma unroll
        for (int j = 0; j < 4; ++j) {
            *(short8*)&Ks[(rr + j * 16) * LP + cg * 8] = kr[j];
            *(short8*)&Vts[(rr + j * 16) * LP + cg * 8] = vr[j];
        }
        __syncthreads();
        if (st < qt) {
            const size_t sn = (size_t)(st + 1) * 64;
#pragma unroll
            for (int j = 0; j < 4; ++j) {
                kr[j] = *(const short8*)(kb + (sn + rr + j * 16) * 3072 + cg * 8);
                vr[j] = *(const short8*)(vtb + (size_t)(rr + j * 16) * TSEQ + sn + cg * 8);
            }
        }

        f32x4 sa[2][4];
#pragma unroll
        for (int mt = 0; mt < 2; ++mt)
#pragma unroll
            for (int nt = 0; nt < 4; ++nt) sa[mt][nt] = zero;
#pragma unroll
        for (int kk = 0; kk < 2; ++kk) {
            short8 aq0 = *(const short8*)&Qs[(wave * 32 + lm) * LP + kk * 32 + quad * 8];
            short8 aq1 = *(const short8*)&Qs[(wave * 32 + 16 + lm) * LP + kk * 32 + quad * 8];
#pragma unroll
            for (int nt = 0; nt < 4; ++nt) {
                short8 bk = *(const short8*)&Ks[(nt * 16 + lm) * LP + kk * 32 + quad * 8];
                sa[0][nt] = mfma_bf16(aq0, bk, sa[0][nt]);
                sa[1][nt] = mfma_bf16(aq1, bk, sa[1][nt]);
            }
        }

        const int s0 = st * 64;
        const bool band = (st == qt);
#pragma unroll
        for (int mt = 0; mt < 2; ++mt) {
            const int qrow = q0 + wave * 32 + mt * 16 + quad * 4;
#pragma unroll
            for (int nt = 0; nt < 4; ++nt) {
                const int col = s0 + nt * 16 + lm;
#pragma unroll
                for (int r = 0; r < 4; ++r) {
                    float p = __expf(0.125f * sa[mt][nt][r]);
                    if (band && col > qrow + r) p = 0.f;
                    lsum[mt][r] += p;
                    Ps[wave][(mt * 16 + quad * 4 + r) * LP + nt * 16 + lm] =
                        (short)(__builtin_bit_cast(uint32_t, p) >> 16);
                }
            }
        }

#pragma unroll
        for (int kk = 0; kk < 2; ++kk) {
            short8 ap0 = *(const short8*)&Ps[wave][lm * LP + kk * 32 + quad * 8];
            short8 ap1 = *(const short8*)&Ps[wave][(16 + lm) * LP + kk * 32 + quad * 8];
#pragma unroll
            for (int t = 0; t < 4; ++t) {
                short8 bv = *(const short8*)&Vts[(t * 16 + lm) * LP + kk * 32 + quad * 8];
                o_acc[0][t] = mfma_bf16(ap0, bv, o_acc[0][t]);
                o_acc[1][t] = mfma_bf16(ap1, bv, o_acc[1][t]);
            }
        }
    }

#pragma unroll
    for (int mt = 0; mt < 2; ++mt)
#pragma unroll
        for (int r = 0; r < 4; ++r) {
            float s = lsum[mt][r];
#pragma unroll
            for (int d = 1; d < 16; d <<= 1) s += __shfl_xor(s, d, 16);
            lsum[mt][r] = s;
        }

#pragma unroll
    for (int mt = 0; mt < 2; ++mt)
#pragma unroll
        for (int r = 0; r < 4; ++r) {
            const float inv = 1.0f / lsum[mt][r];
            const int token = b * TSEQ + q0 + wave * 32 + mt * 16 + quad * 4 + r;
#pragma unroll
            for (int t = 0; t < 4; ++t)
                out[(size_t)token * 1024 + h * 64 + t * 16 + lm] = f2bf(o_acc[mt][t][r] * inv);
        }
}

// ---------------------------------------------------------------------------
// Orchestration
// ---------------------------------------------------------------------------
extern "C" void kernel_launch(void* const* d_in, const int* in_sizes, int n_in,
                              void* d_out, int out_size, void* d_ws, size_t ws_size,
                              hipStream_t stream)
{
    const float* x      = (const float*)d_in[0];
    // d_in[1] = mask (causal, implemented analytically)
    const float* wq     = (const float*)d_in[2];
    const float* wk     = (const float*)d_in[3];
    const float* wv     = (const float*)d_in[4];
    const float* wo     = (const float*)d_in[5];
    const float* w1     = (const float*)d_in[6];
    const float* w2     = (const float*)d_in[7];
    const float* g_attn = (const float*)d_in[8];
    const float* g_ffn  = (const float*)d_in[9];
    float* out = (float*)d_out;

    char* ws = (char*)d_ws;
    const size_t MB = 1024 * 1024;
    // Liveness layout:
    //  0..6   Wqkv_t (dead after QKV)      | FFN2 time: pbuf2 [2][4096][1024] f32
    //  6..8   Wo_t (dead after O-proj)     |   occupies 0..32 (all dead then)
    //  8..16  W1_t (dead after FFN1)
    // 16..24  xn: norm1-out -> attn-out (dead after O-proj)
    // 24..32  hbuf: norm2-out (dead after FFN1)
    // 32..64  qkv -> pbufO (O-proj split-K partials) -> FFN1 out t
    // 64..80  Vt (dead after attn) -> x2 fp32
    // 80..88  W2_t
    short* Wqkv_t = (short*)(ws + 0);
    short* Wo_t   = (short*)(ws + 6 * MB);
    short* W1_t   = (short*)(ws + 8 * MB);
    short* xn     = (short*)(ws + 16 * MB);
    short* hbuf   = (short*)(ws + 24 * MB);
    short* qkv    = (short*)(ws + 32 * MB);
    float* pbufO  = (float*)(ws + 32 * MB);
    short* Vt     = (short*)(ws + 64 * MB);
    float* x2     = (float*)(ws + 64 * MB);
    short* W2_t   = (short*)(ws + 80 * MB);
    float* pbuf2  = (float*)(ws + 0);

    dim3 blk(256);

    transpose_w<<<dim3(16, 16), blk, 0, stream>>>(wq, Wqkv_t, 1024, 1024);
    transpose_w<<<dim3(16, 16), blk, 0, stream>>>(wk, Wqkv_t + (size_t)1024 * 1024, 1024, 1024);
    transpose_w<<<dim3(16, 16), blk, 0, stream>>>(wv, Wqkv_t + (size_t)2048 * 1024, 1024, 1024);
    transpose_w<<<dim3(16, 16), blk, 0, stream>>>(wo, Wo_t, 1024, 1024);
    transpose_w<<<dim3(64, 16), blk, 0, stream>>>(w1, W1_t, 1024, 4096);
    transpose_w<<<dim3(16, 64), blk, 0, stream>>>(w2, W2_t, 4096, 1024);

    rmsnorm_k<<<TOKENS, blk, 0, stream>>>(x, g_attn, xn);

    // qkv = xn @ [Wq|Wk|Wv]   (grid m-fastest: x = m-tiles, y = n-tiles)
    gemm_bt<0><<<dim3(TOKENS / 128, 3072 / 128), blk, 0, stream>>>(
        xn, Wqkv_t, qkv, nullptr, TOKENS, 3072, 1024);

    transpose_v<<<dim3(TSEQ / 64, 32), blk, 0, stream>>>(qkv, Vt);

    attn_k<<<dim3(32, TSEQ / 64), dim3(128), 0, stream>>>(qkv, Vt, xn);

    // O-proj split-K=2, partials into dead qkv region
    gemm_bt<3><<<dim3(TOKENS / 128, 1024 / 128, 2), blk, 0, stream>>>(
        xn, Wo_t, pbufO, nullptr, TOKENS, 1024, 1024);

    // x2 = x + p0 + p1 ; hbuf = rmsnorm(x2)*g_ffn   (fused)
    combine_rms<<<TOKENS, blk, 0, stream>>>(pbufO, x, g_ffn, x2, hbuf);

    // t = silu(h @ W1)  (into qkv region; pbufO dead)
    gemm_bt<2><<<dim3(TOKENS / 128, HIDDEN / 128), blk, 0, stream>>>(
        hbuf, W1_t, qkv, nullptr, TOKENS, HIDDEN, 1024);

    // FFN2 split-K=2
    gemm_bt<3><<<dim3(TOKENS / 128, 1024 / 128, 2), blk, 0, stream>>>(
        qkv, W2_t, pbuf2, nullptr, TOKENS, 1024, HIDDEN);

    combine_k<<<dim3(TOKENS * DIM / 4 / 256), blk, 0, stream>>>(
        pbuf2, x2, out, TOKENS * DIM);
}

// Round 10
// 366.885 us; speedup vs baseline: 1.0844x; 1.0844x over previous
//
#include <hip/hip_runtime.h>
#include <hip/hip_bf16.h>
#include <cstdint>
#include <cstddef>

#define DIM    1024
#define NHEAD  16
#define HDIM   64
#define HIDDEN 4096
#define TSEQ   2048
#define TOKENS 4096  // B*T

typedef __attribute__((ext_vector_type(4))) float  f32x4;
typedef __attribute__((ext_vector_type(8))) short  short8;
typedef __attribute__((ext_vector_type(8))) __bf16 bf16x8;

__device__ __forceinline__ short f2bf(float f) {
    union { float f; uint32_t u; } v; v.f = f;
    uint32_t u = v.u;
    uint32_t r = (u + 0x7fffu + ((u >> 16) & 1u)) >> 16;  // RNE
    return (short)r;
}

__device__ __forceinline__ float bf2f(short s) {
    uint32_t u = ((uint32_t)(uint16_t)s) << 16;
    return __builtin_bit_cast(float, u);
}

__device__ __forceinline__ f32x4 mfma_bf16(short8 a, short8 b, f32x4 c) {
    return __builtin_amdgcn_mfma_f32_16x16x32_bf16(
        __builtin_bit_cast(bf16x8, a), __builtin_bit_cast(bf16x8, b), c, 0, 0, 0);
}

// lgkm-only barrier: does NOT drain vmem, keeps depth-2 register prefetches
// in flight across barriers (validated r8: the only structure so far that
// beats plain __syncthreads).
__device__ __forceinline__ void barrier_lds() {
    asm volatile("s_waitcnt lgkmcnt(0)\n\ts_barrier" ::: "memory");
}

// ---------------------------------------------------------------------------
// Weight transpose + fp32->bf16 convert:  W[K][N] -> Wt[N][K] (bf16)
// ---------------------------------------------------------------------------
__global__ __launch_bounds__(256) void transpose_w(
    const float* __restrict__ W, short* __restrict__ Wt, int K, int N)
{
    __shared__ float tile[64][65];
    const int tid = threadIdx.x;
    const int n0 = blockIdx.x * 64, k0 = blockIdx.y * 64;
    for (int i = tid; i < 4096; i += 256) {
        int r = i >> 6, c = i & 63;
        tile[r][c] = W[(size_t)(k0 + r) * N + n0 + c];
    }
    __syncthreads();
    for (int i = tid; i < 4096; i += 256) {
        int r = i >> 6, c = i & 63;
        Wt[(size_t)(n0 + r) * K + k0 + c] = f2bf(tile[c][r]);
    }
}

// ---------------------------------------------------------------------------
// V transpose: qkv [4096][3072] (V at col 2048 + h*64) -> Vt[bh][64][2048]
// ---------------------------------------------------------------------------
__global__ __launch_bounds__(256) void transpose_v(
    const short* __restrict__ qkv, short* __restrict__ Vt)
{
    __shared__ short tile[64][72];
    const int tid = threadIdx.x;
    const int s0 = blockIdx.x * 64, bh = blockIdx.y;
    const int b = bh >> 4, h = bh & 15;
    const short* src = qkv + ((size_t)(b * TSEQ + s0)) * 3072 + 2048 + h * 64;
    for (int i = tid; i < 512; i += 256) {
        int r = i >> 3, cg = i & 7;
        *(short8*)&tile[r][cg * 8] = *(const short8*)(src + (size_t)r * 3072 + cg * 8);
    }
    __syncthreads();
    short* dst = Vt + ((size_t)bh * 64) * TSEQ + s0;
    for (int i = tid; i < 512; i += 256) {
        int d = i >> 3, sg = i & 7;
        short8 o;
#pragma unroll
        for (int j = 0; j < 8; ++j) o[j] = tile[sg * 8 + j][d];
        *(short8*)(dst + (size_t)d * TSEQ + sg * 8) = o;
    }
}

// ---------------------------------------------------------------------------
// RMSNorm: fp32 in -> bf16 out. One block per token.
// ---------------------------------------------------------------------------
__global__ __launch_bounds__(256) void rmsnorm_k(
    const float* __restrict__ x, const float* __restrict__ g, short* __restrict__ out)
{
    const int t = blockIdx.x, tid = threadIdx.x;
    const int wave = tid >> 6, lane = tid & 63;
    const float4 v = ((const float4*)(x + (size_t)t * DIM))[tid];
    float ss = v.x * v.x + v.y * v.y + v.z * v.z + v.w * v.w;
#pragma unroll
    for (int d = 1; d < 64; d <<= 1) ss += __shfl_xor(ss, d, 64);
    __shared__ float red[4];
    if (lane == 0) red[wave] = ss;
    __syncthreads();
    float tot = red[0] + red[1] + red[2] + red[3];
    float rn = rsqrtf(tot * (1.0f / (float)DIM) + 1e-6f);
    const float4 gv = ((const float4*)g)[tid];
    short4 ov = make_short4(f2bf(v.x * rn * gv.x), f2bf(v.y * rn * gv.y),
                            f2bf(v.z * rn * gv.z), f2bf(v.w * rn * gv.w));
    ((short4*)(out + (size_t)t * DIM))[tid] = ov;
}

// ---------------------------------------------------------------------------
// bf16 GEMM: C[M][N] = A[M][K] * Bt[N][K]^T, 128x128 tile, BK=32, 4 waves.
// R8 skeleton (measured best): two lgkm-only barriers/iter, single 16KB LDS
// buffer, depth-2 register prefetch (loads for tile k+2 issue at iter k).
// Grid m-fastest (m0=blockIdx.x): each XCD pins an m-subset, A rows stay
// L2-resident across n (r9-validated: FETCH 135->41 MB).
// EPI: 0 = bf16 out, 1 = fp32 out + fp32 residual, 2 = SiLU -> bf16 out,
//      3 = BF16 partial out at Cout + z*M*N (split-K)
// ---------------------------------------------------------------------------
template <int EPI>
__global__ __launch_bounds__(256) void gemm_bt(
    const short* __restrict__ A, const short* __restrict__ Bt,
    void* __restrict__ Cout, const float* __restrict__ res,
    int M, int N, int K)
{
    __shared__ short As[128 * 32];
    __shared__ short Bs[128 * 32];
    const int tid  = threadIdx.x;
    const int wave = tid >> 6, lane = tid & 63;
    const int lm = lane & 15, quad = lane >> 4;
    const int wm = wave & 1, wn = wave >> 1;
    const int m0 = blockIdx.x * 128, n0 = blockIdx.y * 128;  // m fastest
    const int Ksl = K / gridDim.z;
    const int kbeg = blockIdx.z * Ksl;
    const int nIter = Ksl >> 5;  // even (>=8) in all launches here

    const f32x4 zero = {0.f, 0.f, 0.f, 0.f};
    f32x4 acc[4][4];
#pragma unroll
    for (int i = 0; i < 4; ++i)
#pragma unroll
        for (int j = 0; j < 4; ++j) acc[i][j] = zero;

    const int lrow = wave * 32 + (lane >> 2);
    const int lcol = (lane & 3) * 8;
    const short* Ap = A + (size_t)(m0 + lrow) * K + kbeg + lcol;
    const short* Bp = Bt + (size_t)(n0 + lrow) * K + kbeg + lcol;
    const int woff = lrow * 32 + lcol;  // +512 for row+16

    short8 a00, a01, b00, b01;  // even tiles
    short8 a10, a11, b10, b11;  // odd tiles

    auto compute = [&]() {
        short8 af[4], bf[4];
#pragma unroll
        for (int mt = 0; mt < 4; ++mt)
            af[mt] = *(const short8*)&As[(wm * 64 + mt * 16 + lm) * 32 + quad * 8];
#pragma unroll
        for (int nt = 0; nt < 4; ++nt)
            bf[nt] = *(const short8*)&Bs[(wn * 64 + nt * 16 + lm) * 32 + quad * 8];
#pragma unroll
        for (int mt = 0; mt < 4; ++mt)
#pragma unroll
            for (int nt = 0; nt < 4; ++nt)
                acc[mt][nt] = mfma_bf16(af[mt], bf[nt], acc[mt][nt]);
    };

    // prologue: tile0 -> set0, tile1 -> set1
    a00 = *(const short8*)Ap;  a01 = *(const short8*)(Ap + (size_t)16 * K);
    b00 = *(const short8*)Bp;  b01 = *(const short8*)(Bp + (size_t)16 * K);
    Ap += 32; Bp += 32;
    a10 = *(const short8*)Ap;  a11 = *(const short8*)(Ap + (size_t)16 * K);
    b10 = *(const short8*)Bp;  b11 = *(const short8*)(Bp + (size_t)16 * K);
    Ap += 32; Bp += 32;

    for (int it = 0; it < nIter; it += 2) {
        // ---- even tile (set0)
        barrier_lds();
        *(short8*)&As[woff] = a00;
        *(short8*)&As[woff + 512] = a01;
        *(short8*)&Bs[woff] = b00;
        *(short8*)&Bs[woff + 512] = b01;
        barrier_lds();
        if (it + 2 < nIter) {
            a00 = *(const short8*)Ap;  a01 = *(const short8*)(Ap + (size_t)16 * K);
            b00 = *(const short8*)Bp;  b01 = *(const short8*)(Bp + (size_t)16 * K);
            Ap += 32; Bp += 32;
        }
        compute();
        // ---- odd tile (set1)
        barrier_lds();
        *(short8*)&As[woff] = a10;
        *(short8*)&As[woff + 512] = a11;
        *(short8*)&Bs[woff] = b10;
        *(short8*)&Bs[woff + 512] = b11;
        barrier_lds();
        if (it + 3 < nIter) {
            a10 = *(const short8*)Ap;  a11 = *(const short8*)(Ap + (size_t)16 * K);
            b10 = *(const short8*)Bp;  b11 = *(const short8*)(Bp + (size_t)16 * K);
            Ap += 32; Bp += 32;
        }
        compute();
    }

#pragma unroll
    for (int mt = 0; mt < 4; ++mt) {
#pragma unroll
        for (int r = 0; r < 4; ++r) {
            const int row = m0 + wm * 64 + mt * 16 + quad * 4 + r;
#pragma unroll
            for (int nt = 0; nt < 4; ++nt) {
                const int col = n0 + wn * 64 + nt * 16 + lm;
                const size_t idx = (size_t)row * N + col;
                const float v = acc[mt][nt][r];
                if constexpr (EPI == 0) {
                    ((short*)Cout)[idx] = f2bf(v);
                } else if constexpr (EPI == 1) {
                    ((float*)Cout)[idx] = res[idx] + v;
                } else if constexpr (EPI == 2) {
                    ((short*)Cout)[idx] = f2bf(v / (1.0f + __expf(-v)));
                } else {
                    ((short*)Cout)[(size_t)blockIdx.z * M * N + idx] = f2bf(v);
                }
            }
        }
    }
}

// ---------------------------------------------------------------------------
// Split-K combine (4 bf16 partials): out = res + sum_{s<4} p[s]
// ---------------------------------------------------------------------------
__global__ __launch_bounds__(256) void combine_k4(
    const short* __restrict__ p, const float* __restrict__ res,
    float* __restrict__ out, int n)
{
    const int i = blockIdx.x * 256 + threadIdx.x;
    if (i * 4 < n) {
        float4 v = ((const float4*)res)[i];
#pragma unroll
        for (int s = 0; s < 4; ++s) {
            short4 ps = ((const short4*)(p + (size_t)s * n))[i];
            v.x += bf2f(ps.x); v.y += bf2f(ps.y);
            v.z += bf2f(ps.z); v.w += bf2f(ps.w);
        }
        ((float4*)out)[i] = v;
    }
}

// ---------------------------------------------------------------------------
// Fused split-K combine (4 bf16 partials) + RMSNorm: one block per token.
//   x2 = res + sum p[s];  nout = bf16(x2 * rsqrt(mean(x2^2)+eps) * g)
// ---------------------------------------------------------------------------
__global__ __launch_bounds__(256) void combine_rms4(
    const short* __restrict__ p, const float* __restrict__ res,
    const float* __restrict__ g, float* __restrict__ x2out,
    short* __restrict__ nout)
{
    const int t = blockIdx.x, tid = threadIdx.x;
    const int wave = tid >> 6, lane = tid & 63;
    const size_t i4 = (size_t)t * 256 + tid;  // float4 index
    float4 v = ((const float4*)res)[i4];
#pragma unroll
    for (int s = 0; s < 4; ++s) {
        short4 ps = ((const short4*)(p + (size_t)s * TOKENS * DIM))[i4];
        v.x += bf2f(ps.x); v.y += bf2f(ps.y);
        v.z += bf2f(ps.z); v.w += bf2f(ps.w);
    }
    ((float4*)x2out)[i4] = v;
    float ss = v.x * v.x + v.y * v.y + v.z * v.z + v.w * v.w;
#pragma unroll
    for (int d = 1; d < 64; d <<= 1) ss += __shfl_xor(ss, d, 64);
    __shared__ float red[4];
    if (lane == 0) red[wave] = ss;
    __syncthreads();
    float tot = red[0] + red[1] + red[2] + red[3];
    float rn = rsqrtf(tot * (1.0f / (float)DIM) + 1e-6f);
    const float4 gv = ((const float4*)g)[tid];
    short4 ov = make_short4(f2bf(v.x * rn * gv.x), f2bf(v.y * rn * gv.y),
                            f2bf(v.z * rn * gv.z), f2bf(v.w * rn * gv.w));
    ((short4*)nout)[i4] = ov;
}

// ---------------------------------------------------------------------------
// Flash attention, causal, fixed-max softmax. 128-thread block = 2 waves x
// 32 q-rows; one block per (bh, 64-row q-tile). Register K/V prefetch.
// ---------------------------------------------------------------------------
#define LP 72
__global__ __launch_bounds__(128) void attn_k(
    const short* __restrict__ qkv, const short* __restrict__ Vt,
    short* __restrict__ out)
{
    __shared__ short Qs[64 * LP];
    __shared__ short Ks[64 * LP];
    __shared__ short Vts[64 * LP];
    __shared__ short Ps[2][32 * LP];

    const int tid = threadIdx.x, wave = tid >> 6, lane = tid & 63;
    const int lm = lane & 15, quad = lane >> 4;
    const int bh = blockIdx.x;
    const int qt = (gridDim.y - 1) - blockIdx.y;  // heavy blocks first
    const int b = bh >> 4, h = bh & 15;
    const int q0 = qt * 64;

    const int rr = tid >> 3, cg = tid & 7;

    const short* qbase = qkv + ((size_t)(b * TSEQ + q0)) * 3072 + h * 64;
#pragma unroll
    for (int j = 0; j < 4; ++j)
        *(short8*)&Qs[(rr + j * 16) * LP + cg * 8] =
            *(const short8*)(qbase + (size_t)(rr + j * 16) * 3072 + cg * 8);

    const short* kb  = qkv + (size_t)b * TSEQ * 3072 + 1024 + h * 64;
    const short* vtb = Vt + (size_t)bh * 64 * TSEQ;

    short8 kr[4], vr[4];
#pragma unroll
    for (int j = 0; j < 4; ++j) {
        kr[j] = *(const short8*)(kb + (size_t)(rr + j * 16) * 3072 + cg * 8);
        vr[j] = *(const short8*)(vtb + (size_t)(rr + j * 16) * TSEQ + cg * 8);
    }

    const f32x4 zero = {0.f, 0.f, 0.f, 0.f};
    f32x4 o_acc[2][4];
#pragma unroll
    for (int mt = 0; mt < 2; ++mt)
#pragma unroll
        for (int t = 0; t < 4; ++t) o_acc[mt][t] = zero;
    float lsum[2][4] = {{0.f, 0.f, 0.f, 0.f}, {0.f, 0.f, 0.f, 0.f}};

    for (int st = 0; st <= qt; ++st) {
        __syncthreads();
#pragma unroll
        for (int j = 0; j < 4; ++j) {
            *(short8*)&Ks[(rr + j * 16) * LP + cg * 8] = kr[j];
            *(short8*)&Vts[(rr + j * 16) * LP + cg * 8] = vr[j];
        }
        __syncthreads();
        if (st < qt) {
            const size_t sn = (size_t)(st + 1) * 64;
#pragma unroll
            for (int j = 0; j < 4; ++j) {
                kr[j] = *(const short8*)(kb + (sn + rr + j * 16) * 3072 + cg * 8);
                vr[j] = *(const short8*)(vtb + (size_t)(rr + j * 16) * TSEQ + sn + cg * 8);
            }
        }

        f32x4 sa[2][4];
#pragma unroll
        for (int mt = 0; mt < 2; ++mt)
#pragma unroll
            for (int nt = 0; nt < 4; ++nt) sa[mt][nt] = zero;
#pragma unroll
        for (int kk = 0; kk < 2; ++kk) {
            short8 aq0 = *(const short8*)&Qs[(wave * 32 + lm) * LP + kk * 32 + quad * 8];
            short8 aq1 = *(const short8*)&Qs[(wave * 32 + 16 + lm) * LP + kk * 32 + quad * 8];
#pragma unroll
            for (int nt = 0; nt < 4; ++nt) {
                short8 bk = *(const short8*)&Ks[(nt * 16 + lm) * LP + kk * 32 + quad * 8];
                sa[0][nt] = mfma_bf16(aq0, bk, sa[0][nt]);
                sa[1][nt] = mfma_bf16(aq1, bk, sa[1][nt]);
            }
        }

        const int s0 = st * 64;
        const bool band = (st == qt);
#pragma unroll
        for (int mt = 0; mt < 2; ++mt) {
            const int qrow = q0 + wave * 32 + mt * 16 + quad * 4;
#pragma unroll
            for (int nt = 0; nt < 4; ++nt) {
                const int col = s0 + nt * 16 + lm;
#pragma unroll
                for (int r = 0; r < 4; ++r) {
                    float p = __expf(0.125f * sa[mt][nt][r]);
                    if (band && col > qrow + r) p = 0.f;
                    lsum[mt][r] += p;
                    Ps[wave][(mt * 16 + quad * 4 + r) * LP + nt * 16 + lm] =
                        (short)(__builtin_bit_cast(uint32_t, p) >> 16);
                }
            }
        }

#pragma unroll
        for (int kk = 0; kk < 2; ++kk) {
            short8 ap0 = *(const short8*)&Ps[wave][lm * LP + kk * 32 + quad * 8];
            short8 ap1 = *(const short8*)&Ps[wave][(16 + lm) * LP + kk * 32 + quad * 8];
#pragma unroll
            for (int t = 0; t < 4; ++t) {
                short8 bv = *(const short8*)&Vts[(t * 16 + lm) * LP + kk * 32 + quad * 8];
                o_acc[0][t] = mfma_bf16(ap0, bv, o_acc[0][t]);
                o_acc[1][t] = mfma_bf16(ap1, bv, o_acc[1][t]);
            }
        }
    }

#pragma unroll
    for (int mt = 0; mt < 2; ++mt)
#pragma unroll
        for (int r = 0; r < 4; ++r) {
            float s = lsum[mt][r];
#pragma unroll
            for (int d = 1; d < 16; d <<= 1) s += __shfl_xor(s, d, 16);
            lsum[mt][r] = s;
        }

#pragma unroll
    for (int mt = 0; mt < 2; ++mt)
#pragma unroll
        for (int r = 0; r < 4; ++r) {
            const float inv = 1.0f / lsum[mt][r];
            const int token = b * TSEQ + q0 + wave * 32 + mt * 16 + quad * 4 + r;
#pragma unroll
            for (int t = 0; t < 4; ++t)
                out[(size_t)token * 1024 + h * 64 + t * 16 + lm] = f2bf(o_acc[mt][t][r] * inv);
        }
}

// ---------------------------------------------------------------------------
// Orchestration
// ---------------------------------------------------------------------------
extern "C" void kernel_launch(void* const* d_in, const int* in_sizes, int n_in,
                              void* d_out, int out_size, void* d_ws, size_t ws_size,
                              hipStream_t stream)
{
    const float* x      = (const float*)d_in[0];
    // d_in[1] = mask (causal, implemented analytically)
    const float* wq     = (const float*)d_in[2];
    const float* wk     = (const float*)d_in[3];
    const float* wv     = (const float*)d_in[4];
    const float* wo     = (const float*)d_in[5];
    const float* w1     = (const float*)d_in[6];
    const float* w2     = (const float*)d_in[7];
    const float* g_attn = (const float*)d_in[8];
    const float* g_ffn  = (const float*)d_in[9];
    float* out = (float*)d_out;

    char* ws = (char*)d_ws;
    const size_t MB = 1024 * 1024;
    // Liveness layout:
    //  0..6   Wqkv_t (dead after QKV)    | FFN2 time: pbuf2 [4][4096][1024] bf16
    //  6..8   Wo_t (dead after O-proj)   |   = 32 MB at 0..32 (all dead then)
    //  8..16  W1_t (dead after FFN1)
    // 16..24  xn: norm1-out -> attn-out (dead after O-proj)
    // 24..32  hbuf: norm2-out (dead after FFN1)
    // 32..64  qkv -> pbufO [4][4096][1024] bf16 (O-proj partials) -> FFN1 out t
    // 64..80  Vt (dead after attn) -> x2 fp32
    // 80..88  W2_t
    short* Wqkv_t = (short*)(ws + 0);
    short* Wo_t   = (short*)(ws + 6 * MB);
    short* W1_t   = (short*)(ws + 8 * MB);
    short* xn     = (short*)(ws + 16 * MB);
    short* hbuf   = (short*)(ws + 24 * MB);
    short* qkv    = (short*)(ws + 32 * MB);
    short* pbufO  = (short*)(ws + 32 * MB);
    short* Vt     = (short*)(ws + 64 * MB);
    float* x2     = (float*)(ws + 64 * MB);
    short* W2_t   = (short*)(ws + 80 * MB);
    short* pbuf2  = (short*)(ws + 0);

    dim3 blk(256);

    transpose_w<<<dim3(16, 16), blk, 0, stream>>>(wq, Wqkv_t, 1024, 1024);
    transpose_w<<<dim3(16, 16), blk, 0, stream>>>(wk, Wqkv_t + (size_t)1024 * 1024, 1024, 1024);
    transpose_w<<<dim3(16, 16), blk, 0, stream>>>(wv, Wqkv_t + (size_t)2048 * 1024, 1024, 1024);
    transpose_w<<<dim3(16, 16), blk, 0, stream>>>(wo, Wo_t, 1024, 1024);
    transpose_w<<<dim3(64, 16), blk, 0, stream>>>(w1, W1_t, 1024, 4096);
    transpose_w<<<dim3(16, 64), blk, 0, stream>>>(w2, W2_t, 4096, 1024);

    rmsnorm_k<<<TOKENS, blk, 0, stream>>>(x, g_attn, xn);

    // qkv = xn @ [Wq|Wk|Wv]   (grid m-fastest)
    gemm_bt<0><<<dim3(TOKENS / 128, 3072 / 128), blk, 0, stream>>>(
        xn, Wqkv_t, qkv, nullptr, TOKENS, 3072, 1024);

    transpose_v<<<dim3(TSEQ / 64, 32), blk, 0, stream>>>(qkv, Vt);

    attn_k<<<dim3(32, TSEQ / 64), dim3(128), 0, stream>>>(qkv, Vt, xn);

    // O-proj split-K=4 (1024 blocks = 4/CU), bf16 partials into dead qkv
    gemm_bt<3><<<dim3(TOKENS / 128, 1024 / 128, 4), blk, 0, stream>>>(
        xn, Wo_t, pbufO, nullptr, TOKENS, 1024, 1024);

    // x2 = x + sum p ; hbuf = rmsnorm(x2)*g_ffn   (fused)
    combine_rms4<<<TOKENS, blk, 0, stream>>>(pbufO, x, g_ffn, x2, hbuf);

    // t = silu(h @ W1)  (into qkv region; pbufO dead)
    gemm_bt<2><<<dim3(TOKENS / 128, HIDDEN / 128), blk, 0, stream>>>(
        hbuf, W1_t, qkv, nullptr, TOKENS, HIDDEN, 1024);

    // FFN2 split-K=4 (1024 blocks = 4/CU), bf16 partials
    gemm_bt<3><<<dim3(TOKENS / 128, 1024 / 128, 4), blk, 0, stream>>>(
        qkv, W2_t, pbuf2, nullptr, TOKENS, 1024, HIDDEN);

    combine_k4<<<dim3(TOKENS * DIM / 4 / 256), blk, 0, stream>>>(
        pbuf2, x2, out, TOKENS * DIM);
}